// Round 1
// 83.236 us; speedup vs baseline: 1.1214x; 1.1214x over previous
//
#include <hip/hip_runtime.h>

#define NFEAT 256
#define NATOMS 4096
#define NCLAUSES 512
#define ROWS 8
#define XPAD 12          // floats per feature column: uniform LDS bank spread
#define BLOCK 256
#define APT (NATOMS / BLOCK)   // 16 contiguous atoms per thread (balanced partition)

// hardware transcendentals: v_exp_f32 computes 2^x
#define EXP2F(v) __builtin_amdgcn_exp2f(v)
#define RCPF(v)  __builtin_amdgcn_rcpf(v)

// Single fused kernel, zero workspace.
//  - thread t owns atoms [16t, 16t+16): uniform trip count (no max-of-64-Poisson
//    exec-mask inflation), contiguous params -> int4/float4 vector loads.
//  - per-atom A,B recomputed inline (replaces cln_pre's abf):
//      e = exp(-z) = exp2(A*x + B); A = -s*K*w ; B = s*K*(eta - eps); K = 100*log2(e)
//  - clause product p = prod(1+e), clamped at 1e37 each step (inf*0 NaN guard),
//    y = sum_c gl[c] * rcp(p_c). Clauses spanning thread boundaries are stitched:
//    each thread publishes its head-clause partial to LDS; the thread holding the
//    clause START gathers forward (sorted cid => span is a contiguous run of
//    pass-through threads). Empty clauses contribute gl[c]*1 via gap detection.
__global__ __launch_bounds__(BLOCK, 4) void cln_fused(
        const float* __restrict__ x, const float* __restrict__ w,
        const float* __restrict__ eta, const float* __restrict__ leaf,
        const float* __restrict__ gate, const int* __restrict__ fid,
        const int* __restrict__ sgn, const int* __restrict__ cid,
        float* __restrict__ y) {
    __shared__ __align__(16) float xT[NFEAT * XPAD];     // 12 KB transposed x tile
    __shared__ float glS[NCLAUSES];                      // 2 KB  gate*leaf
    __shared__ __align__(16) float headPs[BLOCK][ROWS];  // 8 KB  head-clause partials
    __shared__ int headCidS[BLOCK];
    __shared__ int passThruS[BLOCK];                     // whole range one clause & continues
    __shared__ float red[4 * ROWS];

    const int tid = threadIdx.x;
    const int row0 = blockIdx.x * ROWS;
    const float K = 144.269504088896340736f;   // B_CONST * log2(e), B=100

    // Stage 8 rows of x, transposed (coalesced global reads), and gate*leaf.
#pragma unroll
    for (int k = 0; k < ROWS; ++k)
        xT[tid * XPAD + k] = x[(row0 + k) * NFEAT + tid];
    glS[tid]         = gate[tid] * leaf[tid];
    glS[tid + BLOCK] = gate[tid + BLOCK] * leaf[tid + BLOCK];

    const int a0 = tid * APT;
    const int prev = (tid == 0) ? -1 : cid[a0 - 1];
    int cur = cid[a0];
    const bool headPartial = (cur == prev);    // head clause continues from prior thread
    headCidS[tid] = cur;

    __syncthreads();

    float acc[ROWS], p[ROWS];
#pragma unroll
    for (int r = 0; r < ROWS; ++r) { acc[r] = 0.f; p[r] = 1.f; }

    // empty clauses in the gap before our first clause (owned by the thread whose
    // range starts a new clause; tid 0 covers clauses 0..cid[0]-1)
    float gapAdd = 0.f;
    if (!headPartial)
        for (int c = prev + 1; c < cur; ++c) gapAdd += glS[c];

    bool headOpen = true;   // still accumulating the first clause of our range

    for (int ch = 0; ch < APT / 4; ++ch) {
        const int base = a0 + ch * 4;
        const int4   c4 = *(const int4*)(cid + base);
        const int4   f4 = *(const int4*)(fid + base);
        const int4   s4 = *(const int4*)(sgn + base);
        const float4 w4 = *(const float4*)(w + base);
        const float4 t4 = *(const float4*)(eta + base);
        const int   cidv[4] = {c4.x, c4.y, c4.z, c4.w};
        const int   fidv[4] = {f4.x, f4.y, f4.z, f4.w};
        const int   sgnv[4] = {s4.x, s4.y, s4.z, s4.w};
        const float wv[4]   = {w4.x, w4.y, w4.z, w4.w};
        const float etv[4]  = {t4.x, t4.y, t4.z, t4.w};

#pragma unroll
        for (int j = 0; j < 4; ++j) {
            const int c = cidv[j];
            if (c != cur) {
                // close clause 'cur'
                if (headOpen && headPartial) {
                    // head clause started in a prior thread: publish partial
                    *(float4*)&headPs[tid][0] = make_float4(p[0], p[1], p[2], p[3]);
                    *(float4*)&headPs[tid][4] = make_float4(p[4], p[5], p[6], p[7]);
                } else {
                    const float g = glS[cur];
#pragma unroll
                    for (int r = 0; r < ROWS; ++r) acc[r] = fmaf(g, RCPF(p[r]), acc[r]);
                }
                headOpen = false;
                for (int cc = cur + 1; cc < c; ++cc) gapAdd += glS[cc];  // empty clauses
#pragma unroll
                for (int r = 0; r < ROWS; ++r) p[r] = 1.f;
                cur = c;
            }
            // eval atom: identical math to previous kernel (bitwise)
            const float s  = (sgnv[j] == 0) ? -1.f : 1.f;
            const float A  = -s * K * wv[j];
            const float Bc =  s * K * (etv[j] - 0.01f);
            const int xo = fidv[j] * XPAD;
            const float4 xa = *(const float4*)(xT + xo);
            const float4 xb = *(const float4*)(xT + xo + 4);
            const float xv[ROWS] = {xa.x, xa.y, xa.z, xa.w, xb.x, xb.y, xb.z, xb.w};
#pragma unroll
            for (int r = 0; r < ROWS; ++r) {
                const float e = EXP2F(fmaf(A, xv[r], Bc));
                p[r] = fminf(fmaf(p[r], e, p[r]), 1e37f);   // p *= (1+e), clamped
            }
        }
    }

    // tail clause of our range
    const int nxt = (tid == BLOCK - 1) ? -2 : cid[a0 + APT];
    const bool tailCont = (nxt == cur);
    const bool single = headOpen;              // whole range was one clause
    passThruS[tid] = (single && tailCont) ? 1 : 0;
    bool owner = false;
    if (single && headPartial) {
        // entire range is a continuation: publish, an upstream thread owns it
        *(float4*)&headPs[tid][0] = make_float4(p[0], p[1], p[2], p[3]);
        *(float4*)&headPs[tid][4] = make_float4(p[4], p[5], p[6], p[7]);
    } else if (tailCont) {
        owner = true;                          // clause starts here, spans forward
    } else {
        const float g = glS[cur];
#pragma unroll
        for (int r = 0; r < ROWS; ++r) acc[r] = fmaf(g, RCPF(p[r]), acc[r]);
    }
    if (tid == BLOCK - 1)                      // empty clauses after the last atom
        for (int cc = cur + 1; cc < NCLAUSES; ++cc) gapAdd += glS[cc];

    __syncthreads();

    if (owner) {
        // gather the spanning clause's partials from following threads.
        // sorted cid => contiguous run; headCid mismatch or !passThru terminates.
        for (int t = tid + 1; t < BLOCK; ++t) {
            if (headCidS[t] != cur) break;
            const float4 h0 = *(const float4*)&headPs[t][0];
            const float4 h1 = *(const float4*)&headPs[t][4];
            p[0] *= h0.x; p[1] *= h0.y; p[2] *= h0.z; p[3] *= h0.w;
            p[4] *= h1.x; p[5] *= h1.y; p[6] *= h1.z; p[7] *= h1.w;
            if (!passThruS[t]) break;
        }
        // factors >= 1 so products never hit inf*0: rcp(inf)=0 matches underflow
        const float g = glS[cur];
#pragma unroll
        for (int r = 0; r < ROWS; ++r) acc[r] = fmaf(g, RCPF(p[r]), acc[r]);
    }

#pragma unroll
    for (int r = 0; r < ROWS; ++r) acc[r] += gapAdd;   // empty clauses: gl * rcp(1)

    // Block reduction: wave shuffle-reduce each row, then 4 partials via LDS.
    const int wave = tid >> 6;
    const int lane = tid & 63;
#pragma unroll
    for (int r = 0; r < ROWS; ++r) {
        float v = acc[r];
#pragma unroll
        for (int off = 32; off > 0; off >>= 1)
            v += __shfl_down(v, off, 64);
        if (lane == 0) red[wave * ROWS + r] = v;
    }
    __syncthreads();
    if (tid < ROWS)
        y[row0 + tid] = red[tid] + red[ROWS + tid] + red[2 * ROWS + tid] + red[3 * ROWS + tid];
}

extern "C" void kernel_launch(void* const* d_in, const int* in_sizes, int n_in,
                              void* d_out, int out_size, void* d_ws, size_t ws_size,
                              hipStream_t stream) {
    const float* x    = (const float*)d_in[0];
    const float* w    = (const float*)d_in[1];
    const float* eta  = (const float*)d_in[2];
    const float* leaf = (const float*)d_in[3];
    const float* gate = (const float*)d_in[4];
    const int*   fid  = (const int*)d_in[5];
    const int*   sgn  = (const int*)d_in[6];
    const int*   cid  = (const int*)d_in[7];
    float* y = (float*)d_out;
    (void)d_ws; (void)ws_size; (void)n_in; (void)out_size;

    const int bsz = in_sizes[0] / NFEAT;  // 8192
    cln_fused<<<bsz / ROWS, BLOCK, 0, stream>>>(x, w, eta, leaf, gate, fid, sgn, cid, y);
}